// Round 12
// baseline (114.508 us; speedup 1.0000x reference)
//
#include <hip/hip_runtime.h>
#include <hip/hip_bf16.h>
#include <math.h>
#include <stdint.h>

// ---------------------------------------------------------------------------
// Attention (B=4, N=2048, D=512, H=8, Dh=64) for MI355X.
// Precision plan (threshold 6.48e-3 absolute; measured floor 1.95e-3):
//   x@Wqkv Q/K cols: 2-term (ah*bh + ah*bl); V cols 1-term.
//   QK^T: plain bf16.  PV: bf16 P,V.  AO bf16; out GEMM 1-term.
// R12: flash split-KV (2-way): grid 1024 (16qb x 32bh x 2 halves) ->
// 3 blocks/CU resident, 12 waves/CU (was grid-capped at 8). Blocks write
// unnormalized partial O (f32) + per-row m,s; k_combine merges exactly in
// log2 domain. Per-wave inner loop identical to R11.
// ---------------------------------------------------------------------------

typedef unsigned short u16;
typedef __attribute__((ext_vector_type(4))) float f32x4;
typedef __attribute__((ext_vector_type(8))) short bf16x8;   // 8 bf16 = 4 VGPRs
typedef __attribute__((ext_vector_type(4))) short s16x4;

#define AS1 __attribute__((address_space(1)))
#define AS3 __attribute__((address_space(3)))
#define MFMA(a, b, c) __builtin_amdgcn_mfma_f32_16x16x32_bf16(a, b, c, 0, 0, 0)
#define QSCALE 0.180336880f   /* 0.125 * log2(e): logits in log2 domain */

__device__ __forceinline__ u16 f2bf(float f) {
  union { float f; unsigned u; } v; v.f = f;
  unsigned r = v.u + 0x7FFFu + ((v.u >> 16) & 1u);   // RNE
  return (u16)(r >> 16);
}
__device__ __forceinline__ float bf2f(u16 b) {
  union { unsigned u; float f; } v; v.u = ((unsigned)b) << 16; return v.f;
}
__device__ __forceinline__ void splitbf(float x, u16& hi, u16& lo) {
  hi = f2bf(x); lo = f2bf(x - bf2f(hi));
}
__device__ __forceinline__ void gld16(const u16* g, u16* l) {
  __builtin_amdgcn_global_load_lds((const AS1 void*)g, (AS3 void*)l, 16, 0, 0);
}
__device__ __forceinline__ float u2f(unsigned u) {
  union { unsigned u; float f; } v; v.u = u; return v.f;
}
__device__ __forceinline__ unsigned f2u(float f) {
  union { float f; unsigned u; } v; v.f = f; return v.u;
}
__device__ __forceinline__ int cvtpk(float lo, float hi) {
  int r; asm("v_cvt_pk_bf16_f32 %0, %1, %2" : "=v"(r) : "v"(lo), "v"(hi));
  return r;
}
__device__ __forceinline__ float fexp2(float x) {
  float r; asm("v_exp_f32 %0, %1" : "=v"(r) : "v"(x));
  return r;
}

// ---------------- prep kernels -------------------------------------------
__global__ void k_cast(const float* __restrict__ s, u16* __restrict__ h, int n) {
  int i = (blockIdx.x * 256 + threadIdx.x) * 4;
  if (i < n) {
    f32x4 v = *(const f32x4*)&s[i];
    s16x4 hh;
    #pragma unroll
    for (int j = 0; j < 4; ++j) hh[j] = (short)f2bf(v[j]);
    *(s16x4*)&h[i] = hh;
  }
}

// src [512][N] row-major -> dst [N][512] (transposed), split hi/lo
__global__ void k_tsplit(const float* __restrict__ s, u16* __restrict__ h,
                         u16* __restrict__ l, int N, int total) {
  int i = blockIdx.x * 256 + threadIdx.x;          // i = n*512 + k
  if (i < total) {
    int n = i >> 9, k = i & 511;
    u16 a, b; splitbf(s[(size_t)k * N + n], a, b);
    h[i] = a; l[i] = b;
  }
}

// ---------------- shared GEMM core: C[128x128] tile, K=512, BK=32 ----------
// TERMS=1: ah*bh.  TERMS=2: ah*bh + ah*bl (exact-x_hat * W).
template <int TERMS>
__device__ __forceinline__ void gemm_core(
    const u16* __restrict__ Ah,
    const u16* __restrict__ Bh, const u16* __restrict__ Bl,
    char* sm, int rowA, int rowB, int tid, f32x4 (&acc)[4][4]) {
  const int wid = tid >> 6, lane = tid & 63;
  const int x = lane & 15, h = lane >> 4;
  const int wr = wid >> 1, wc = wid & 1;
  const int d0 = wid * 1024 + lane * 16;
  const int lg0 = d0 ^ (((d0 >> 7) & 7) << 4);
  const int srow = lg0 >> 6;
  const int scol = (lg0 & 63) >> 1;
  const int swk = ((lane >> 1) & 7) << 4;
  const char* smA = sm + (((wr * 64 + x) * 64 + h * 16) ^ swk);
  const char* smB = sm + (((wc * 64 + x) * 64 + h * 16) ^ swk);

  for (int kt = 0; kt < 16; ++kt) {
    const int kofs = kt * 32;
    __syncthreads();
    #pragma unroll
    for (int r = 0; r < 2; ++r) {
      const int row  = r * 64 + srow;
      const int ldst = r * 4096 + wid * 1024;
      const size_t ga = (size_t)(rowA + row) * 512 + kofs + scol;
      const size_t gb = (size_t)(rowB + row) * 512 + kofs + scol;
      gld16(Ah + ga, (u16*)(sm + ldst));
      gld16(Bh + gb, (u16*)(sm + 16384 + ldst));
      if (TERMS == 2) gld16(Bl + gb, (u16*)(sm + 24576 + ldst));
    }
    __syncthreads();
    bf16x8 a_h[4], b_h[4], b_l[4];
    #pragma unroll
    for (int i = 0; i < 4; ++i)
      a_h[i] = *(const bf16x8*)(smA + i * 1024);
    #pragma unroll
    for (int j = 0; j < 4; ++j) {
      b_h[j] = *(const bf16x8*)(smB + 16384 + j * 1024);
      if (TERMS == 2) b_l[j] = *(const bf16x8*)(smB + 24576 + j * 1024);
    }
    __builtin_amdgcn_s_setprio(1);
    #pragma unroll
    for (int i = 0; i < 4; ++i)
      #pragma unroll
      for (int j = 0; j < 4; ++j) {
        acc[i][j] = MFMA(a_h[i], b_h[j], acc[i][j]);
        if (TERMS == 2) acc[i][j] = MFMA(a_h[i], b_l[j], acc[i][j]);
      }
    __builtin_amdgcn_s_setprio(0);
  }
}

// ---------------- QKV projection -------------------------------------------
__global__ __launch_bounds__(256) void k_gemm_qkv(
    const u16* __restrict__ Ah,
    const u16* __restrict__ Bh, const u16* __restrict__ Bl,
    u16* __restrict__ Qb, u16* __restrict__ Kb, u16* __restrict__ Vt) {
  __shared__ __align__(1024) char sm[32768];
  const int tid = threadIdx.x, lane = tid & 63, wid = tid >> 6;
  const int x = lane & 15, h = lane >> 4;
  const int wr = wid >> 1, wc = wid & 1;
  const int rowA = blockIdx.x * 128, rowB = blockIdx.y * 128;
  f32x4 acc[4][4] = {};
  if (rowB >= 1024)
    gemm_core<1>(Ah, Bh, Bl, sm, rowA, rowB, tid, acc);
  else
    gemm_core<2>(Ah, Bh, Bl, sm, rowA, rowB, tid, acc);

  #pragma unroll
  for (int i = 0; i < 4; ++i)
    #pragma unroll
    for (int j = 0; j < 4; ++j) {
      const int n = rowB + wc * 64 + j * 16 + x;
      const int which = n >> 9;
      const int hh = (n >> 6) & 7, d = n & 63;
      const int m0 = rowA + wr * 64 + i * 16 + h * 4;
      const int b = m0 >> 11, is0 = m0 & 2047;
      if (which == 0) {
        #pragma unroll
        for (int r = 0; r < 4; ++r) {
          const size_t idx = ((size_t)((b * 8 + hh) * 2048 + is0 + r)) * 64 + d;
          Qb[idx] = f2bf(acc[i][j][r] * QSCALE);
        }
      } else if (which == 1) {
        #pragma unroll
        for (int r = 0; r < 4; ++r) {
          const size_t idx = ((size_t)((b * 8 + hh) * 2048 + is0 + r)) * 64 + d;
          Kb[idx] = f2bf(acc[i][j][r]);
        }
      } else {
        s16x4 vv;
        #pragma unroll
        for (int r = 0; r < 4; ++r) vv[r] = (short)f2bf(acc[i][j][r]);
        *(s16x4*)&Vt[((size_t)((b * 8 + hh) * 64 + d)) * 2048 + is0] = vv;
      }
    }
}

// ---------------- output projection (1-term bf16) --------------------------
__global__ __launch_bounds__(256) void k_gemm_out(
    const u16* __restrict__ Ah, const u16* __restrict__ Bh,
    const float* __restrict__ bias, float* __restrict__ out) {
  __shared__ __align__(1024) char sm[32768];
  const int tid = threadIdx.x, lane = tid & 63, wid = tid >> 6;
  const int x = lane & 15, h = lane >> 4;
  const int wr = wid >> 1, wc = wid & 1;
  const int rowA = blockIdx.x * 128, rowB = blockIdx.y * 128;
  f32x4 acc[4][4] = {};
  gemm_core<1>(Ah, Bh, Bh, sm, rowA, rowB, tid, acc);

  #pragma unroll
  for (int i = 0; i < 4; ++i)
    #pragma unroll
    for (int j = 0; j < 4; ++j) {
      const int n = rowB + wc * 64 + j * 16 + x;
      #pragma unroll
      for (int r = 0; r < 4; ++r) {
        const int m = rowA + wr * 64 + i * 16 + h * 4 + r;
        out[(size_t)m * 512 + n] = acc[i][j][r] + bias[n];
      }
    }
}

// ---------------- flash attention, split-KV half ----------------------------
// Grid 1024 (16qb x 32bh x 2 halves, XCD-swizzled), 256 thr = 4 waves x 32 q.
// Each block: 16 KV tiles (half the sequence). Writes unnormalized partial O
// (f32), per-row m (log2 domain) and s to workspace. Inner loop = R11.
// LDS: KV dbuf 2x16KB + 4x per-wave P 4KB = 48KB -> 3 blocks/CU resident.
__global__ __launch_bounds__(256, 3) void k_attn(
    const u16* __restrict__ Qb,
    const u16* __restrict__ Kb, const u16* __restrict__ Vt,
    float* __restrict__ OP,        // [2][32*2048*64] via +half*15728640
    float* __restrict__ Mm,        // [2][65536]
    float* __restrict__ Sm) {      // [2][65536]
  __shared__ __align__(1024) char sm[49152];
  const int tid = threadIdx.x, wid = tid >> 6, lane = tid & 63;
  const int x = lane & 15, h = lane >> 4;

  // XCD swizzle: l bijective; halves of same (qb,bh) adjacent -> same XCD
  const int fid = blockIdx.x;
  const int l = (fid & 7) * 128 + (fid >> 3);
  const int half = l & 1, qb = (l >> 1) & 15, bh = l >> 5;

  const size_t base = (size_t)bh * 2048 * 64;   // Q/K [bh][2048][64]; Vt [bh][64][2048]
  const int qr0 = qb * 128 + wid * 32;
  const int kt0 = half * 16;                     // first KV tile of this half

  // Q B-frags per group g: lane (x,h) holds Q[qr0+g*16+x][d=ks*32+h*8+j]
  bf16x8 qh[2][2];
  #pragma unroll
  for (int g = 0; g < 2; ++g) {
    const size_t rq = base + (size_t)(qr0 + g * 16 + x) * 64 + h * 8;
    #pragma unroll
    for (int ks = 0; ks < 2; ++ks)
      qh[g][ks] = *(const bf16x8*)&Qb[rq + ks * 32];
  }

  bf16x8 ones;
  #pragma unroll
  for (int j = 0; j < 8; ++j) ones[j] = (short)0x3F80;   // bf16 1.0

  // staging map (256 thr): dest byte db = tid*16 within each 4KB chunk
  const int db = tid * 16;
  const int lg = db ^ (((db >> 7) & 7) << 4);
  const int srow = lg >> 6;             // 0..63
  const int scb  = (lg & 63) >> 1;      // u16 col within 32-wide row
  const size_t offK = (size_t)srow * 64 + scb;
  const size_t offV = (size_t)srow * 2048 + scb;

  const int swk = ((lane >> 1) & 7) << 4;   // read xor for 64B-row tiles
  const int rdo = (x * 64 + h * 16) ^ swk;  // per-lane K/V read base offset
  char* const pb = sm + 32768 + wid * 4096; // per-wave P buffer [32q][64kv]
  const int pxor = (x & 7) << 4;            // P row swizzle
  const int prow = x * 128;                 // P row base (g adds 2048)

  float mrun[2] = {-INFINITY, -INFINITY};
  f32x4 o[2][4] = {};
  f32x4 os[2] = {};

  {  // stage tile kt0 -> buf0 (4 loads/thread)
    const size_t kB = base + (size_t)kt0 * 64 * 64;
    const size_t vB = base + (size_t)kt0 * 64;
    gld16(Kb + kB + offK,      (u16*)(sm + db));
    gld16(Kb + kB + offK + 32, (u16*)(sm + 4096 + db));
    gld16(Vt + vB + offV,      (u16*)(sm + 8192 + db));
    gld16(Vt + vB + offV + 32, (u16*)(sm + 12288 + db));
  }

  for (int kv = 0; kv < 16; ++kv) {
    const int bb = (kv & 1) * 16384;
    __builtin_amdgcn_s_barrier();
    if (kv < 15) {
      const size_t kvb = (size_t)(kt0 + kv + 1) * 64;
      char* buf = sm + (16384 - bb);
      gld16(Kb + base + kvb * 64 + offK,      (u16*)(buf + db));
      gld16(Kb + base + kvb * 64 + offK + 32, (u16*)(buf + 4096 + db));
      gld16(Vt + base + kvb + offV,           (u16*)(buf + 8192 + db));
      gld16(Vt + base + kvb + offV + 32,      (u16*)(buf + 12288 + db));
      asm volatile("s_waitcnt vmcnt(4)" ::: "memory");  // prev tile landed
    } else {
      asm volatile("s_waitcnt vmcnt(0)" ::: "memory");
    }
    __builtin_amdgcn_s_barrier();

    const char* smb = sm + bb + rdo;

    // ---- S^T = K Q^T (bf16; Q pre-scaled by 0.125*log2e)
    f32x4 s[2][4] = {};
    __builtin_amdgcn_s_setprio(1);
    #pragma unroll
    for (int c = 0; c < 4; ++c)
      #pragma unroll
      for (int ks = 0; ks < 2; ++ks) {
        bf16x8 kb_ = *(const bf16x8*)(smb + ks * 4096 + c * 1024);
        s[0][c] = MFMA(kb_, qh[0][ks], s[0][c]);
        s[1][c] = MFMA(kb_, qh[1][ks], s[1][c]);
      }
    __builtin_amdgcn_s_setprio(0);

    // ---- per-group row max (16 local) + 2-shfl cross reduce over h-lanes
    float pm[2];
    #pragma unroll
    for (int g = 0; g < 2; ++g) {
      float m0 = fmaxf(fmaxf(s[g][0][0], s[g][0][1]), s[g][0][2]);
      float m1 = fmaxf(fmaxf(s[g][0][3], s[g][1][0]), s[g][1][1]);
      float m2 = fmaxf(fmaxf(s[g][1][2], s[g][1][3]), s[g][2][0]);
      float m3 = fmaxf(fmaxf(s[g][2][1], s[g][2][2]), s[g][2][3]);
      float m4 = fmaxf(fmaxf(s[g][3][0], s[g][3][1]), s[g][3][2]);
      float m5 = fmaxf(fmaxf(m0, m1), m2);
      float p  = fmaxf(fmaxf(fmaxf(m3, m4), s[g][3][3]), m5);
      p = fmaxf(p, __shfl_xor(p, 16, 64));
      p = fmaxf(p, __shfl_xor(p, 32, 64));
      pm[g] = p;
    }

    // ---- defer-rescale (THR=7 in log2; P bounded by 128)
    if (__any((pm[0] > mrun[0] + 7.0f) || (pm[1] > mrun[1] + 7.0f))) {
      #pragma unroll
      for (int g = 0; g < 2; ++g) {
        float mnew = fmaxf(mrun[g], pm[g]);
        float scl = fexp2(mrun[g] - mnew);
        mrun[g] = mnew;
        #pragma unroll
        for (int r = 0; r < 4; ++r) {
          float sq = u2f((unsigned)__builtin_amdgcn_ds_bpermute(
              (20 * h + r) * 4, (int)f2u(scl)));
          os[g][r] *= sq;
          #pragma unroll
          for (int dg = 0; dg < 4; ++dg) o[g][dg][r] *= sq;
        }
      }
    }

    // ---- P = exp2(S - mrun) -> bf16 pairs -> per-wave LDS [32q][64kv]
    #pragma unroll
    for (int g = 0; g < 2; ++g)
      #pragma unroll
      for (int c = 0; c < 4; ++c) {
        int w0 = cvtpk(fexp2(s[g][c][0] - mrun[g]),
                       fexp2(s[g][c][1] - mrun[g]));
        int w1 = cvtpk(fexp2(s[g][c][2] - mrun[g]),
                       fexp2(s[g][c][3] - mrun[g]));
        int* dst = (int*)(pb + g * 2048 + prow + ((c * 32 + h * 8) ^ pxor));
        dst[0] = w0; dst[1] = w1;
      }

    // ---- PV + row-sum (P A-frags re-read from LDS; same-wave, no barrier)
    __builtin_amdgcn_s_setprio(1);
    #pragma unroll
    for (int ch = 0; ch < 2; ++ch) {
      bf16x8 pa0 = *(const bf16x8*)(pb + prow +
                                    ((ch * 64 + h * 16) ^ pxor));
      bf16x8 pa1 = *(const bf16x8*)(pb + 2048 + prow +
                                    ((ch * 64 + h * 16) ^ pxor));
      os[0] = MFMA(pa0, ones, os[0]);
      os[1] = MFMA(pa1, ones, os[1]);
      #pragma unroll
      for (int dg = 0; dg < 4; ++dg) {
        bf16x8 vb = *(const bf16x8*)(smb + 8192 + ch * 4096 + dg * 1024);
        o[0][dg] = MFMA(pa0, vb, o[0][dg]);
        o[1][dg] = MFMA(pa1, vb, o[1][dg]);
      }
    }
    __builtin_amdgcn_s_setprio(0);
  }

  // ---- write partial O (f32, unnormalized), m (h==0), s (x==0)
  float* op = OP + (size_t)half * 15728640 +
              ((size_t)(bh * 2048 + qr0)) * 64;
  #pragma unroll
  for (int g = 0; g < 2; ++g) {
    #pragma unroll
    for (int r = 0; r < 4; ++r) {
      const int row = g * 16 + h * 4 + r;
      #pragma unroll
      for (int dg = 0; dg < 4; ++dg)
        op[(size_t)row * 64 + dg * 16 + x] = o[g][dg][r];
      if (x == 0)
        Sm[half * 65536 + bh * 2048 + qr0 + g * 16 + h * 4 + r] = os[g][r];
    }
    if (h == 0)
      Mm[half * 65536 + bh * 2048 + qr0 + g * 16 + x] = mrun[g];
  }
}

// ---------------- combine: merge the two KV halves --------------------------
// 1,048,576 threads: gi -> (rb = bh*2048+row, d4). Exact log2-domain merge.
__global__ __launch_bounds__(256) void k_combine(
    const float* __restrict__ OP, const float* __restrict__ Mm,
    const float* __restrict__ Sm, u16* __restrict__ AO) {
  const int gi = blockIdx.x * 256 + threadIdx.x;
  const int d4 = (gi & 15) * 4;
  const int rb = gi >> 4;                    // bh*2048 + row
  const float m1 = Mm[rb], m2 = Mm[65536 + rb];
  const float s1 = Sm[rb], s2 = Sm[65536 + rb];
  const float m = fmaxf(m1, m2);
  const float a1 = fexp2(m1 - m), a2 = fexp2(m2 - m);
  const float inv = 1.0f / (s1 * a1 + s2 * a2);
  const float w1 = a1 * inv, w2 = a2 * inv;
  f32x4 o1 = *(const f32x4*)&OP[(size_t)rb * 64 + d4];
  f32x4 o2 = *(const f32x4*)&OP[15728640 + (size_t)rb * 64 + d4];
  const int bh = rb >> 11, row = rb & 2047;
  const int b = bh >> 3, head = bh & 7;
  s16x4 r_;
  #pragma unroll
  for (int j = 0; j < 4; ++j) r_[j] = (short)f2bf(o1[j] * w1 + o2[j] * w2);
  *(s16x4*)&AO[((size_t)(b * 2048 + row)) * 512 + head * 64 + d4] = r_;
}

// ---------------------------------------------------------------------------
extern "C" void kernel_launch(void* const* d_in, const int* in_sizes, int n_in,
                              void* d_out, int out_size, void* d_ws, size_t ws_size,
                              hipStream_t stream) {
  const float* x    = (const float*)d_in[0];
  const float* wqkv = (const float*)d_in[1];
  const float* wout = (const float*)d_in[2];
  const float* bout = (const float*)d_in[3];
  float* out = (float*)d_out;

  char* w = (char*)d_ws;
  // Phase-1 buffers (dead after k_gemm_qkv): xh, wqh, wql
  u16* xh  = (u16*)(w + 0);           // 8192x512 bf16 (8MB)
  u16* wqh = (u16*)(w + 16777216);    // WqkvT [1536][512]
  u16* wql = (u16*)(w + 18350080);
  u16* woh = (u16*)(w + 19922944);    // WoutT [512][512] (live to end)
  u16* wol = (u16*)(w + 20447232);    // (written, unused)
  u16* Qb  = (u16*)(w + 20971520);    // [32][2048][64] bf16 (pre-scaled)
  u16* Kb  = (u16*)(w + 37748736);    // [32][2048][64] bf16
  u16* Vt  = (u16*)(w + 46137344);    // [32][64][2048] bf16
  u16* AO  = (u16*)(w + 54525952);    // [8192][512] bf16
  // Split-KV partials (alias phase-1 regions; attn runs after qkv):
  float* OP = (float*)(w + 0);        // half0 f32 16.78MB at 0; half1 at:
                                      //   +15728640 f32 = byte 62914560
  float* Mm = (float*)(w + 16777216); // [2][65536] f32
  float* Sm = (float*)(w + 17301504); // [2][65536] f32

  k_cast  <<<4096, 256, 0, stream>>>(x, xh, 4194304);
  k_tsplit<<<3072, 256, 0, stream>>>(wqkv, wqh, wql, 1536, 786432);
  k_tsplit<<<1024, 256, 0, stream>>>(wout, woh, wol, 512, 262144);
  k_gemm_qkv<<<dim3(64, 12), 256, 0, stream>>>(xh, wqh, wql, Qb, Kb, Vt);
  k_attn<<<1024, 256, 0, stream>>>(Qb, Kb, Vt, OP, Mm, Sm);
  k_combine<<<4096, 256, 0, stream>>>(OP, Mm, Sm, AO);
  k_gemm_out<<<dim3(64, 4), 256, 0, stream>>>(AO, woh, bout, out);
}

// Round 13
// 107.235 us; speedup vs baseline: 1.0678x; 1.0678x over previous
//
#include <hip/hip_runtime.h>
#include <hip/hip_bf16.h>
#include <math.h>
#include <stdint.h>

// ---------------------------------------------------------------------------
// Attention (B=4, N=2048, D=512, H=8, Dh=64) for MI355X.
// Precision plan (threshold 6.48e-3 absolute; measured floor 1.95e-3):
//   x@Wqkv Q/K cols: 2-term (ah*bh + ah*bl); V cols 1-term.
//   QK^T: plain bf16.  PV: bf16 P,V.  AO bf16; out GEMM 1-term.
// R13: revert split-KV (R12 net loss: no throughput gain, +combine tax).
// R11 body + KV tile 128 (2x 64-kv sub-tiles per barrier-pair) -> half the
// barrier/vmcnt overhead per kv element. LDS 80KB (KV dbuf 2x32KB + P 16KB),
// grid 512 = 2 blocks/CU even.
// ---------------------------------------------------------------------------

typedef unsigned short u16;
typedef __attribute__((ext_vector_type(4))) float f32x4;
typedef __attribute__((ext_vector_type(8))) short bf16x8;   // 8 bf16 = 4 VGPRs
typedef __attribute__((ext_vector_type(4))) short s16x4;

#define AS1 __attribute__((address_space(1)))
#define AS3 __attribute__((address_space(3)))
#define MFMA(a, b, c) __builtin_amdgcn_mfma_f32_16x16x32_bf16(a, b, c, 0, 0, 0)
#define QSCALE 0.180336880f   /* 0.125 * log2(e): logits in log2 domain */

__device__ __forceinline__ u16 f2bf(float f) {
  union { float f; unsigned u; } v; v.f = f;
  unsigned r = v.u + 0x7FFFu + ((v.u >> 16) & 1u);   // RNE
  return (u16)(r >> 16);
}
__device__ __forceinline__ float bf2f(u16 b) {
  union { unsigned u; float f; } v; v.u = ((unsigned)b) << 16; return v.f;
}
__device__ __forceinline__ void splitbf(float x, u16& hi, u16& lo) {
  hi = f2bf(x); lo = f2bf(x - bf2f(hi));
}
__device__ __forceinline__ void gld16(const u16* g, u16* l) {
  __builtin_amdgcn_global_load_lds((const AS1 void*)g, (AS3 void*)l, 16, 0, 0);
}
__device__ __forceinline__ float u2f(unsigned u) {
  union { unsigned u; float f; } v; v.u = u; return v.f;
}
__device__ __forceinline__ unsigned f2u(float f) {
  union { float f; unsigned u; } v; v.f = f; return v.u;
}
__device__ __forceinline__ int cvtpk(float lo, float hi) {
  int r; asm("v_cvt_pk_bf16_f32 %0, %1, %2" : "=v"(r) : "v"(lo), "v"(hi));
  return r;
}
__device__ __forceinline__ float fexp2(float x) {
  float r; asm("v_exp_f32 %0, %1" : "=v"(r) : "v"(x));
  return r;
}

// ---------------- prep kernels -------------------------------------------
__global__ void k_cast(const float* __restrict__ s, u16* __restrict__ h, int n) {
  int i = (blockIdx.x * 256 + threadIdx.x) * 4;
  if (i < n) {
    f32x4 v = *(const f32x4*)&s[i];
    s16x4 hh;
    #pragma unroll
    for (int j = 0; j < 4; ++j) hh[j] = (short)f2bf(v[j]);
    *(s16x4*)&h[i] = hh;
  }
}

// src [512][N] row-major -> dst [N][512] (transposed), split hi/lo
__global__ void k_tsplit(const float* __restrict__ s, u16* __restrict__ h,
                         u16* __restrict__ l, int N, int total) {
  int i = blockIdx.x * 256 + threadIdx.x;          // i = n*512 + k
  if (i < total) {
    int n = i >> 9, k = i & 511;
    u16 a, b; splitbf(s[(size_t)k * N + n], a, b);
    h[i] = a; l[i] = b;
  }
}

// ---------------- shared GEMM core: C[128x128] tile, K=512, BK=32 ----------
// TERMS=1: ah*bh.  TERMS=2: ah*bh + ah*bl (exact-x_hat * W).
template <int TERMS>
__device__ __forceinline__ void gemm_core(
    const u16* __restrict__ Ah,
    const u16* __restrict__ Bh, const u16* __restrict__ Bl,
    char* sm, int rowA, int rowB, int tid, f32x4 (&acc)[4][4]) {
  const int wid = tid >> 6, lane = tid & 63;
  const int x = lane & 15, h = lane >> 4;
  const int wr = wid >> 1, wc = wid & 1;
  const int d0 = wid * 1024 + lane * 16;
  const int lg0 = d0 ^ (((d0 >> 7) & 7) << 4);
  const int srow = lg0 >> 6;
  const int scol = (lg0 & 63) >> 1;
  const int swk = ((lane >> 1) & 7) << 4;
  const char* smA = sm + (((wr * 64 + x) * 64 + h * 16) ^ swk);
  const char* smB = sm + (((wc * 64 + x) * 64 + h * 16) ^ swk);

  for (int kt = 0; kt < 16; ++kt) {
    const int kofs = kt * 32;
    __syncthreads();
    #pragma unroll
    for (int r = 0; r < 2; ++r) {
      const int row  = r * 64 + srow;
      const int ldst = r * 4096 + wid * 1024;
      const size_t ga = (size_t)(rowA + row) * 512 + kofs + scol;
      const size_t gb = (size_t)(rowB + row) * 512 + kofs + scol;
      gld16(Ah + ga, (u16*)(sm + ldst));
      gld16(Bh + gb, (u16*)(sm + 16384 + ldst));
      if (TERMS == 2) gld16(Bl + gb, (u16*)(sm + 24576 + ldst));
    }
    __syncthreads();
    bf16x8 a_h[4], b_h[4], b_l[4];
    #pragma unroll
    for (int i = 0; i < 4; ++i)
      a_h[i] = *(const bf16x8*)(smA + i * 1024);
    #pragma unroll
    for (int j = 0; j < 4; ++j) {
      b_h[j] = *(const bf16x8*)(smB + 16384 + j * 1024);
      if (TERMS == 2) b_l[j] = *(const bf16x8*)(smB + 24576 + j * 1024);
    }
    __builtin_amdgcn_s_setprio(1);
    #pragma unroll
    for (int i = 0; i < 4; ++i)
      #pragma unroll
      for (int j = 0; j < 4; ++j) {
        acc[i][j] = MFMA(a_h[i], b_h[j], acc[i][j]);
        if (TERMS == 2) acc[i][j] = MFMA(a_h[i], b_l[j], acc[i][j]);
      }
    __builtin_amdgcn_s_setprio(0);
  }
}

// ---------------- QKV projection -------------------------------------------
__global__ __launch_bounds__(256) void k_gemm_qkv(
    const u16* __restrict__ Ah,
    const u16* __restrict__ Bh, const u16* __restrict__ Bl,
    u16* __restrict__ Qb, u16* __restrict__ Kb, u16* __restrict__ Vt) {
  __shared__ __align__(1024) char sm[32768];
  const int tid = threadIdx.x, lane = tid & 63, wid = tid >> 6;
  const int x = lane & 15, h = lane >> 4;
  const int wr = wid >> 1, wc = wid & 1;
  const int rowA = blockIdx.x * 128, rowB = blockIdx.y * 128;
  f32x4 acc[4][4] = {};
  if (rowB >= 1024)
    gemm_core<1>(Ah, Bh, Bl, sm, rowA, rowB, tid, acc);
  else
    gemm_core<2>(Ah, Bh, Bl, sm, rowA, rowB, tid, acc);

  #pragma unroll
  for (int i = 0; i < 4; ++i)
    #pragma unroll
    for (int j = 0; j < 4; ++j) {
      const int n = rowB + wc * 64 + j * 16 + x;
      const int which = n >> 9;
      const int hh = (n >> 6) & 7, d = n & 63;
      const int m0 = rowA + wr * 64 + i * 16 + h * 4;
      const int b = m0 >> 11, is0 = m0 & 2047;
      if (which == 0) {
        #pragma unroll
        for (int r = 0; r < 4; ++r) {
          const size_t idx = ((size_t)((b * 8 + hh) * 2048 + is0 + r)) * 64 + d;
          Qb[idx] = f2bf(acc[i][j][r] * QSCALE);
        }
      } else if (which == 1) {
        #pragma unroll
        for (int r = 0; r < 4; ++r) {
          const size_t idx = ((size_t)((b * 8 + hh) * 2048 + is0 + r)) * 64 + d;
          Kb[idx] = f2bf(acc[i][j][r]);
        }
      } else {
        s16x4 vv;
        #pragma unroll
        for (int r = 0; r < 4; ++r) vv[r] = (short)f2bf(acc[i][j][r]);
        *(s16x4*)&Vt[((size_t)((b * 8 + hh) * 64 + d)) * 2048 + is0] = vv;
      }
    }
}

// ---------------- output projection (1-term bf16) --------------------------
__global__ __launch_bounds__(256) void k_gemm_out(
    const u16* __restrict__ Ah, const u16* __restrict__ Bh,
    const float* __restrict__ bias, float* __restrict__ out) {
  __shared__ __align__(1024) char sm[32768];
  const int tid = threadIdx.x, lane = tid & 63, wid = tid >> 6;
  const int x = lane & 15, h = lane >> 4;
  const int wr = wid >> 1, wc = wid & 1;
  const int rowA = blockIdx.x * 128, rowB = blockIdx.y * 128;
  f32x4 acc[4][4] = {};
  gemm_core<1>(Ah, Bh, Bh, sm, rowA, rowB, tid, acc);

  #pragma unroll
  for (int i = 0; i < 4; ++i)
    #pragma unroll
    for (int j = 0; j < 4; ++j) {
      const int n = rowB + wc * 64 + j * 16 + x;
      #pragma unroll
      for (int r = 0; r < 4; ++r) {
        const int m = rowA + wr * 64 + i * 16 + h * 4 + r;
        out[(size_t)m * 512 + n] = acc[i][j][r] + bias[n];
      }
    }
}

// ---------------- flash attention (16x16 MFMA, KV tile 128) -----------------
// Grid 512 blocks (XCD-swizzled), 256 thr = 4 waves x 32 q-rows (QBLK=128).
// KV tile 128 per barrier-pair (2x 64-kv sub-tiles) -> half the sync overhead
// vs R11.  Per wave: 2 q-groups of 16 share every K/V fragment read.
// Swapped QK^T (bf16): lane (x,h) holds S^T[k=c*16+h*4+r][q=g*16+x].
// P -> per-wave LDS [32 q][64 kv] (128B rows, ^((q&7)<<4) swizzle) -> PV
// A-frags.  Row-sum via MFMA(P, ones).  Defer-rescale THR=7.
// LDS: KV dbuf 2x32KB {per buf: K sub0 8K, K sub1 8K, V sub0 8K, V sub1 8K}
// + 4x per-wave P 4KB = 80KB -> 2 blocks/CU (grid 512 = exactly 2/CU).
__global__ __launch_bounds__(256, 2) void k_attn(
    const u16* __restrict__ Qb,
    const u16* __restrict__ Kb, const u16* __restrict__ Vt,
    u16* __restrict__ AO) {
  __shared__ __align__(1024) char sm[81920];
  const int tid = threadIdx.x, wid = tid >> 6, lane = tid & 63;
  const int x = lane & 15, h = lane >> 4;

  // XCD-aware swizzle (512 % 8 == 0): 4 consecutive bh per XCD (2MB KV in L2)
  const int fid = blockIdx.x;
  const int l = (fid & 7) * 64 + (fid >> 3);
  const int qb = l & 15, bh = l >> 4;

  const size_t base = (size_t)bh * 2048 * 64;   // Q/K [bh][2048][64]; Vt [bh][64][2048]
  const int qr0 = qb * 128 + wid * 32;

  // Q B-frags per group g: lane (x,h) holds Q[qr0+g*16+x][d=ks*32+h*8+j]
  bf16x8 qh[2][2];
  #pragma unroll
  for (int g = 0; g < 2; ++g) {
    const size_t rq = base + (size_t)(qr0 + g * 16 + x) * 64 + h * 8;
    #pragma unroll
    for (int ks = 0; ks < 2; ++ks)
      qh[g][ks] = *(const bf16x8*)&Qb[rq + ks * 32];
  }

  bf16x8 ones;
  #pragma unroll
  for (int j = 0; j < 8; ++j) ones[j] = (short)0x3F80;   // bf16 1.0

  // staging map (256 thr): dest byte db = tid*16 within each 4KB chunk
  const int db = tid * 16;
  const int lg = db ^ (((db >> 7) & 7) << 4);
  const int srow = lg >> 6;             // 0..63
  const int scb  = (lg & 63) >> 1;      // u16 col within 32-wide row
  const size_t offK = (size_t)srow * 64 + scb;
  const size_t offV = (size_t)srow * 2048 + scb;

  const int swk = ((lane >> 1) & 7) << 4;   // read xor for 64B-row tiles
  const int rdo = (x * 64 + h * 16) ^ swk;  // per-lane K/V read base offset
  char* const pb = sm + 65536 + wid * 4096; // per-wave P buffer [32q][64kv]
  const int pxor = (x & 7) << 4;            // P row swizzle
  const int prow = x * 128;                 // P row base (g adds 2048)

  float mrun[2] = {-INFINITY, -INFINITY};
  f32x4 o[2][4] = {};
  f32x4 os[2] = {};

  {  // stage tile 0 (kv 0..127) -> buf0 (8 loads/thread)
    #pragma unroll
    for (int sub = 0; sub < 2; ++sub) {
      const size_t kS = base + (size_t)(sub * 64) * 64 + offK;
      const size_t vS = base + (size_t)(sub * 64) + offV;
      const int d0 = sub * 8192 + db;
      gld16(Kb + kS,      (u16*)(sm + d0));
      gld16(Kb + kS + 32, (u16*)(sm + 4096 + d0));
      gld16(Vt + vS,      (u16*)(sm + 16384 + d0));
      gld16(Vt + vS + 32, (u16*)(sm + 20480 + d0));
    }
  }

  for (int kt = 0; kt < 16; ++kt) {
    const int bb = (kt & 1) * 32768;
    __builtin_amdgcn_s_barrier();
    if (kt < 15) {
      const size_t kvb = (size_t)(kt + 1) * 128;
      char* buf = sm + (32768 - bb);
      #pragma unroll
      for (int sub = 0; sub < 2; ++sub) {
        const size_t kS = base + (kvb + sub * 64) * 64 + offK;
        const size_t vS = base + kvb + sub * 64 + offV;
        const int d0 = sub * 8192 + db;
        gld16(Kb + kS,      (u16*)(buf + d0));
        gld16(Kb + kS + 32, (u16*)(buf + 4096 + d0));
        gld16(Vt + vS,      (u16*)(buf + 16384 + d0));
        gld16(Vt + vS + 32, (u16*)(buf + 20480 + d0));
      }
      asm volatile("s_waitcnt vmcnt(8)" ::: "memory");  // prev tile landed
    } else {
      asm volatile("s_waitcnt vmcnt(0)" ::: "memory");
    }
    __builtin_amdgcn_s_barrier();

    #pragma unroll
    for (int sub = 0; sub < 2; ++sub) {
      const char* smb = sm + bb + sub * 8192 + rdo;

      // ---- S^T = K Q^T (bf16; Q pre-scaled by 0.125*log2e)
      f32x4 s[2][4] = {};
      __builtin_amdgcn_s_setprio(1);
      #pragma unroll
      for (int c = 0; c < 4; ++c)
        #pragma unroll
        for (int ks = 0; ks < 2; ++ks) {
          bf16x8 kb_ = *(const bf16x8*)(smb + ks * 4096 + c * 1024);
          s[0][c] = MFMA(kb_, qh[0][ks], s[0][c]);
          s[1][c] = MFMA(kb_, qh[1][ks], s[1][c]);
        }
      __builtin_amdgcn_s_setprio(0);

      // ---- per-group row max (16 local) + 2-shfl cross reduce over h-lanes
      float pm[2];
      #pragma unroll
      for (int g = 0; g < 2; ++g) {
        float m0 = fmaxf(fmaxf(s[g][0][0], s[g][0][1]), s[g][0][2]);
        float m1 = fmaxf(fmaxf(s[g][0][3], s[g][1][0]), s[g][1][1]);
        float m2 = fmaxf(fmaxf(s[g][1][2], s[g][1][3]), s[g][2][0]);
        float m3 = fmaxf(fmaxf(s[g][2][1], s[g][2][2]), s[g][2][3]);
        float m4 = fmaxf(fmaxf(s[g][3][0], s[g][3][1]), s[g][3][2]);
        float m5 = fmaxf(fmaxf(m0, m1), m2);
        float p  = fmaxf(fmaxf(fmaxf(m3, m4), s[g][3][3]), m5);
        p = fmaxf(p, __shfl_xor(p, 16, 64));
        p = fmaxf(p, __shfl_xor(p, 32, 64));
        pm[g] = p;
      }

      // ---- defer-rescale (THR=7 in log2; P bounded by 128)
      if (__any((pm[0] > mrun[0] + 7.0f) || (pm[1] > mrun[1] + 7.0f))) {
        #pragma unroll
        for (int g = 0; g < 2; ++g) {
          float mnew = fmaxf(mrun[g], pm[g]);
          float scl = fexp2(mrun[g] - mnew);
          mrun[g] = mnew;
          #pragma unroll
          for (int r = 0; r < 4; ++r) {
            float sq = u2f((unsigned)__builtin_amdgcn_ds_bpermute(
                (20 * h + r) * 4, (int)f2u(scl)));
            os[g][r] *= sq;
            #pragma unroll
            for (int dg = 0; dg < 4; ++dg) o[g][dg][r] *= sq;
          }
        }
      }

      // ---- P = exp2(S - mrun) -> bf16 pairs -> per-wave LDS [32q][64kv]
      #pragma unroll
      for (int g = 0; g < 2; ++g)
        #pragma unroll
        for (int c = 0; c < 4; ++c) {
          int w0 = cvtpk(fexp2(s[g][c][0] - mrun[g]),
                         fexp2(s[g][c][1] - mrun[g]));
          int w1 = cvtpk(fexp2(s[g][c][2] - mrun[g]),
                         fexp2(s[g][c][3] - mrun[g]));
          int* dst = (int*)(pb + g * 2048 + prow + ((c * 32 + h * 8) ^ pxor));
          dst[0] = w0; dst[1] = w1;
        }

      // ---- PV + row-sum (P A-frags re-read from LDS; same-wave, no barrier)
      __builtin_amdgcn_s_setprio(1);
      #pragma unroll
      for (int ch = 0; ch < 2; ++ch) {
        bf16x8 pa0 = *(const bf16x8*)(pb + prow +
                                      ((ch * 64 + h * 16) ^ pxor));
        bf16x8 pa1 = *(const bf16x8*)(pb + 2048 + prow +
                                      ((ch * 64 + h * 16) ^ pxor));
        os[0] = MFMA(pa0, ones, os[0]);
        os[1] = MFMA(pa1, ones, os[1]);
        #pragma unroll
        for (int dg = 0; dg < 4; ++dg) {
          bf16x8 vb = *(const bf16x8*)(smb + 16384 + ch * 4096 + dg * 1024);
          o[0][dg] = MFMA(pa0, vb, o[0][dg]);
          o[1][dg] = MFMA(pa1, vb, o[1][dg]);
        }
      }
      __builtin_amdgcn_s_setprio(0);
    }
  }

  // ---- normalize (os[g][r] = rowsum for q = g*16+h*4+r), write AO bf16
  const int b_ = bh >> 3, head = bh & 7;
  #pragma unroll
  for (int g = 0; g < 2; ++g)
    #pragma unroll
    for (int r = 0; r < 4; ++r) {
      const float inv = 1.0f / os[g][r];
      const int row = qr0 + g * 16 + h * 4 + r;
      #pragma unroll
      for (int dg = 0; dg < 4; ++dg) {
        AO[((size_t)(b_ * 2048 + row)) * 512 + head * 64 + dg * 16 + x] =
            f2bf(o[g][dg][r] * inv);
      }
    }
}

// ---------------------------------------------------------------------------
extern "C" void kernel_launch(void* const* d_in, const int* in_sizes, int n_in,
                              void* d_out, int out_size, void* d_ws, size_t ws_size,
                              hipStream_t stream) {
  const float* x    = (const float*)d_in[0];
  const float* wqkv = (const float*)d_in[1];
  const float* wout = (const float*)d_in[2];
  const float* bout = (const float*)d_in[3];
  float* out = (float*)d_out;

  char* w = (char*)d_ws;
  u16* xh  = (u16*)(w + 0);           // 8192x512 bf16
  u16* wqh = (u16*)(w + 16777216);    // WqkvT [1536][512]
  u16* wql = (u16*)(w + 18350080);
  u16* woh = (u16*)(w + 19922944);    // WoutT [512][512]
  u16* wol = (u16*)(w + 20447232);    // (written, unused)
  u16* Qb  = (u16*)(w + 20971520);    // [32][2048][64] bf16 (pre-scaled)
  u16* Kb  = (u16*)(w + 37748736);    // [32][2048][64] bf16
  u16* Vt  = (u16*)(w + 46137344);    // [32][64][2048] bf16
  u16* AO  = (u16*)(w + 54525952);    // [8192][512] bf16; end 62914560

  k_cast  <<<4096, 256, 0, stream>>>(x, xh, 4194304);
  k_tsplit<<<3072, 256, 0, stream>>>(wqkv, wqh, wql, 1536, 786432);
  k_tsplit<<<1024, 256, 0, stream>>>(wout, woh, wol, 512, 262144);
  k_gemm_qkv<<<dim3(64, 12), 256, 0, stream>>>(xh, wqh, wql, Qb, Kb, Vt);
  k_attn<<<512, 256, 0, stream>>>(Qb, Kb, Vt, AO);
  k_gemm_out<<<dim3(64, 4), 256, 0, stream>>>(AO, woh, bout, out);
}

// Round 14
// 106.699 us; speedup vs baseline: 1.0732x; 1.0050x over previous
//
#include <hip/hip_runtime.h>
#include <hip/hip_bf16.h>
#include <math.h>
#include <stdint.h>

// ---------------------------------------------------------------------------
// Attention (B=4, N=2048, D=512, H=8, Dh=64) for MI355X.
// Precision plan (threshold 6.48e-3; measured floor 1.95e-3):
//   x@Wqkv: 1-term bf16 (x_hat * W_hat).  QK^T: bf16.  PV: bf16 P,V.
//   AO bf16; out GEMM 1-term.  Split-KV partials bf16, m/s f32.
// R14: occupancy attack -> 8-wave blocks x 2-way split-KV (grid 512,
// 64KB LDS, 2 blocks/CU = 16 waves/CU = 4/SIMD, 2x latency hiding; KV
// staged once per 256 q-rows). bf16 partial O + R12-verified combine.
// 1-term QKV GEMM (W-lo dropped; noise ~ Q/K bf16 rounding already absorbed).
// ---------------------------------------------------------------------------

typedef unsigned short u16;
typedef __attribute__((ext_vector_type(4))) float f32x4;
typedef __attribute__((ext_vector_type(8))) short bf16x8;   // 8 bf16 = 4 VGPRs
typedef __attribute__((ext_vector_type(4))) short s16x4;

#define AS1 __attribute__((address_space(1)))
#define AS3 __attribute__((address_space(3)))
#define MFMA(a, b, c) __builtin_amdgcn_mfma_f32_16x16x32_bf16(a, b, c, 0, 0, 0)
#define QSCALE 0.180336880f   /* 0.125 * log2(e): logits in log2 domain */

__device__ __forceinline__ u16 f2bf(float f) {
  union { float f; unsigned u; } v; v.f = f;
  unsigned r = v.u + 0x7FFFu + ((v.u >> 16) & 1u);   // RNE
  return (u16)(r >> 16);
}
__device__ __forceinline__ float bf2f(u16 b) {
  union { unsigned u; float f; } v; v.u = ((unsigned)b) << 16; return v.f;
}
__device__ __forceinline__ void gld16(const u16* g, u16* l) {
  __builtin_amdgcn_global_load_lds((const AS1 void*)g, (AS3 void*)l, 16, 0, 0);
}
__device__ __forceinline__ float u2f(unsigned u) {
  union { unsigned u; float f; } v; v.u = u; return v.f;
}
__device__ __forceinline__ unsigned f2u(float f) {
  union { float f; unsigned u; } v; v.f = f; return v.u;
}
__device__ __forceinline__ int cvtpk(float lo, float hi) {
  int r; asm("v_cvt_pk_bf16_f32 %0, %1, %2" : "=v"(r) : "v"(lo), "v"(hi));
  return r;
}
__device__ __forceinline__ float fexp2(float x) {
  float r; asm("v_exp_f32 %0, %1" : "=v"(r) : "v"(x));
  return r;
}

// ---------------- prep kernels -------------------------------------------
__global__ void k_cast(const float* __restrict__ s, u16* __restrict__ h, int n) {
  int i = (blockIdx.x * 256 + threadIdx.x) * 4;
  if (i < n) {
    f32x4 v = *(const f32x4*)&s[i];
    s16x4 hh;
    #pragma unroll
    for (int j = 0; j < 4; ++j) hh[j] = (short)f2bf(v[j]);
    *(s16x4*)&h[i] = hh;
  }
}

// src [512][N] row-major -> dst [N][512] transposed bf16 cast
__global__ void k_tcast(const float* __restrict__ s, u16* __restrict__ h,
                        int N, int total) {
  int i = blockIdx.x * 256 + threadIdx.x;          // i = n*512 + k
  if (i < total) {
    int n = i >> 9, k = i & 511;
    h[i] = f2bf(s[(size_t)k * N + n]);
  }
}

// ---------------- shared GEMM core: C[128x128] tile, K=512, BK=32, 1-term --
__device__ __forceinline__ void gemm_core(
    const u16* __restrict__ Ah, const u16* __restrict__ Bh,
    char* sm, int rowA, int rowB, int tid, f32x4 (&acc)[4][4]) {
  const int wid = tid >> 6, lane = tid & 63;
  const int x = lane & 15, h = lane >> 4;
  const int wr = wid >> 1, wc = wid & 1;
  const int d0 = wid * 1024 + lane * 16;
  const int lg0 = d0 ^ (((d0 >> 7) & 7) << 4);
  const int srow = lg0 >> 6;
  const int scol = (lg0 & 63) >> 1;
  const int swk = ((lane >> 1) & 7) << 4;
  const char* smA = sm + (((wr * 64 + x) * 64 + h * 16) ^ swk);
  const char* smB = sm + (((wc * 64 + x) * 64 + h * 16) ^ swk);

  for (int kt = 0; kt < 16; ++kt) {
    const int kofs = kt * 32;
    __syncthreads();
    #pragma unroll
    for (int r = 0; r < 2; ++r) {
      const int row  = r * 64 + srow;
      const int ldst = r * 4096 + wid * 1024;
      const size_t ga = (size_t)(rowA + row) * 512 + kofs + scol;
      const size_t gb = (size_t)(rowB + row) * 512 + kofs + scol;
      gld16(Ah + ga, (u16*)(sm + ldst));
      gld16(Bh + gb, (u16*)(sm + 16384 + ldst));
    }
    __syncthreads();
    bf16x8 a_h[4], b_h[4];
    #pragma unroll
    for (int i = 0; i < 4; ++i)
      a_h[i] = *(const bf16x8*)(smA + i * 1024);
    #pragma unroll
    for (int j = 0; j < 4; ++j)
      b_h[j] = *(const bf16x8*)(smB + 16384 + j * 1024);
    __builtin_amdgcn_s_setprio(1);
    #pragma unroll
    for (int i = 0; i < 4; ++i)
      #pragma unroll
      for (int j = 0; j < 4; ++j)
        acc[i][j] = MFMA(a_h[i], b_h[j], acc[i][j]);
    __builtin_amdgcn_s_setprio(0);
  }
}

// ---------------- QKV projection (1-term) ----------------------------------
__global__ __launch_bounds__(256) void k_gemm_qkv(
    const u16* __restrict__ Ah, const u16* __restrict__ Bh,
    u16* __restrict__ Qb, u16* __restrict__ Kb, u16* __restrict__ Vt) {
  __shared__ __align__(1024) char sm[32768];
  const int tid = threadIdx.x, lane = tid & 63, wid = tid >> 6;
  const int x = lane & 15, h = lane >> 4;
  const int wr = wid >> 1, wc = wid & 1;
  const int rowA = blockIdx.x * 128, rowB = blockIdx.y * 128;
  f32x4 acc[4][4] = {};
  gemm_core(Ah, Bh, sm, rowA, rowB, tid, acc);

  #pragma unroll
  for (int i = 0; i < 4; ++i)
    #pragma unroll
    for (int j = 0; j < 4; ++j) {
      const int n = rowB + wc * 64 + j * 16 + x;
      const int which = n >> 9;
      const int hh = (n >> 6) & 7, d = n & 63;
      const int m0 = rowA + wr * 64 + i * 16 + h * 4;
      const int b = m0 >> 11, is0 = m0 & 2047;
      if (which == 0) {
        #pragma unroll
        for (int r = 0; r < 4; ++r) {
          const size_t idx = ((size_t)((b * 8 + hh) * 2048 + is0 + r)) * 64 + d;
          Qb[idx] = f2bf(acc[i][j][r] * QSCALE);
        }
      } else if (which == 1) {
        #pragma unroll
        for (int r = 0; r < 4; ++r) {
          const size_t idx = ((size_t)((b * 8 + hh) * 2048 + is0 + r)) * 64 + d;
          Kb[idx] = f2bf(acc[i][j][r]);
        }
      } else {
        s16x4 vv;
        #pragma unroll
        for (int r = 0; r < 4; ++r) vv[r] = (short)f2bf(acc[i][j][r]);
        *(s16x4*)&Vt[((size_t)((b * 8 + hh) * 64 + d)) * 2048 + is0] = vv;
      }
    }
}

// ---------------- output projection (1-term bf16) --------------------------
__global__ __launch_bounds__(256) void k_gemm_out(
    const u16* __restrict__ Ah, const u16* __restrict__ Bh,
    const float* __restrict__ bias, float* __restrict__ out) {
  __shared__ __align__(1024) char sm[32768];
  const int tid = threadIdx.x, lane = tid & 63, wid = tid >> 6;
  const int x = lane & 15, h = lane >> 4;
  const int wr = wid >> 1, wc = wid & 1;
  const int rowA = blockIdx.x * 128, rowB = blockIdx.y * 128;
  f32x4 acc[4][4] = {};
  gemm_core(Ah, Bh, sm, rowA, rowB, tid, acc);

  #pragma unroll
  for (int i = 0; i < 4; ++i)
    #pragma unroll
    for (int j = 0; j < 4; ++j) {
      const int n = rowB + wc * 64 + j * 16 + x;
      #pragma unroll
      for (int r = 0; r < 4; ++r) {
        const int m = rowA + wr * 64 + i * 16 + h * 4 + r;
        out[(size_t)m * 512 + n] = acc[i][j][r] + bias[n];
      }
    }
}

// ---------------- flash attention, split-KV half, 8-wave blocks -------------
// Grid 512 (8qb x 32bh x 2 halves, XCD-swizzled), 512 thr = 8 waves x 32 q.
// Each block: 16 KV tiles (half seq), KV staged once per 256 q-rows.
// Per-wave body identical to R11 (2 q-groups share K/V fragment reads).
// LDS: KV dbuf 2x16KB {K 8KB, V 8KB} + 8x per-wave P 4KB = 64KB -> 2 blk/CU
// = 16 waves/CU.  Staging 2 gld16/thread, vmcnt(2).  Partial O bf16 + m,s f32.
__global__ __launch_bounds__(512, 2) void k_attn(
    const u16* __restrict__ Qb,
    const u16* __restrict__ Kb, const u16* __restrict__ Vt,
    u16* __restrict__ OP,          // [2][32*2048*64] bf16 (+half*4194304)
    float* __restrict__ Mm,        // [2][65536]
    float* __restrict__ Sm) {      // [2][65536]
  __shared__ __align__(1024) char sm[65536];
  const int tid = threadIdx.x, wid = tid >> 6, lane = tid & 63;
  const int x = lane & 15, h = lane >> 4;

  // XCD swizzle: 4 bh per XCD; halves of same (qb,bh) on same XCD
  const int fid = blockIdx.x;
  const int l = (fid & 7) * 64 + (fid >> 3);
  const int half = l & 1, qb = (l >> 1) & 7, bh = l >> 4;

  const size_t base = (size_t)bh * 2048 * 64;   // Q/K [bh][2048][64]; Vt [bh][64][2048]
  const int qr0 = qb * 256 + wid * 32;
  const size_t kv0 = (size_t)half * 1024;        // first kv of this half

  // Q B-frags per group g: lane (x,h) holds Q[qr0+g*16+x][d=ks*32+h*8+j]
  bf16x8 qh[2][2];
  #pragma unroll
  for (int g = 0; g < 2; ++g) {
    const size_t rq = base + (size_t)(qr0 + g * 16 + x) * 64 + h * 8;
    #pragma unroll
    for (int ks = 0; ks < 2; ++ks)
      qh[g][ks] = *(const bf16x8*)&Qb[rq + ks * 32];
  }

  bf16x8 ones;
  #pragma unroll
  for (int j = 0; j < 8; ++j) ones[j] = (short)0x3F80;   // bf16 1.0

  // staging map (512 thr): K image [0,8K) dest db=tid*16; V image [8K,16K)
  const int db = tid * 16;
  const int lg = db ^ (((db >> 7) & 7) << 4);
  const int sks  = db >> 12;            // chunk (bit 12 untouched by xor)
  const int srow = (lg >> 6) & 63;
  const int scb  = (lg & 63) >> 1;
  const size_t offK = (size_t)srow * 64 + sks * 32 + scb;    // + kvb*64
  const size_t offV = (size_t)srow * 2048 + sks * 32 + scb;  // + kvb

  const int swk = ((lane >> 1) & 7) << 4;   // read xor for 64B-row tiles
  const int rdo = (x * 64 + h * 16) ^ swk;  // per-lane K/V read base offset
  char* const pb = sm + 32768 + wid * 4096; // per-wave P buffer [32q][64kv]
  const int pxor = (x & 7) << 4;            // P row swizzle
  const int prow = x * 128;                 // P row base (g adds 2048)

  float mrun[2] = {-INFINITY, -INFINITY};
  f32x4 o[2][4] = {};
  f32x4 os[2] = {};

  {  // stage tile 0 of this half -> buf0 (2 loads/thread)
    gld16(Kb + base + kv0 * 64 + offK, (u16*)(sm + db));
    gld16(Vt + base + kv0 + offV,      (u16*)(sm + 8192 + db));
  }

  for (int kv = 0; kv < 16; ++kv) {
    const int bb = (kv & 1) * 16384;
    __builtin_amdgcn_s_barrier();
    if (kv < 15) {
      const size_t kvb = kv0 + (size_t)(kv + 1) * 64;
      char* buf = sm + (16384 - bb);
      gld16(Kb + base + kvb * 64 + offK, (u16*)(buf + db));
      gld16(Vt + base + kvb + offV,      (u16*)(buf + 8192 + db));
      asm volatile("s_waitcnt vmcnt(2)" ::: "memory");  // prev tile landed
    } else {
      asm volatile("s_waitcnt vmcnt(0)" ::: "memory");
    }
    __builtin_amdgcn_s_barrier();

    const char* smb = sm + bb + rdo;

    // ---- S^T = K Q^T (bf16; Q pre-scaled by 0.125*log2e)
    f32x4 s[2][4] = {};
    __builtin_amdgcn_s_setprio(1);
    #pragma unroll
    for (int c = 0; c < 4; ++c)
      #pragma unroll
      for (int ks = 0; ks < 2; ++ks) {
        bf16x8 kb_ = *(const bf16x8*)(smb + ks * 4096 + c * 1024);
        s[0][c] = MFMA(kb_, qh[0][ks], s[0][c]);
        s[1][c] = MFMA(kb_, qh[1][ks], s[1][c]);
      }
    __builtin_amdgcn_s_setprio(0);

    // ---- per-group row max (16 local) + 2-shfl cross reduce over h-lanes
    float pm[2];
    #pragma unroll
    for (int g = 0; g < 2; ++g) {
      float m0 = fmaxf(fmaxf(s[g][0][0], s[g][0][1]), s[g][0][2]);
      float m1 = fmaxf(fmaxf(s[g][0][3], s[g][1][0]), s[g][1][1]);
      float m2 = fmaxf(fmaxf(s[g][1][2], s[g][1][3]), s[g][2][0]);
      float m3 = fmaxf(fmaxf(s[g][2][1], s[g][2][2]), s[g][2][3]);
      float m4 = fmaxf(fmaxf(s[g][3][0], s[g][3][1]), s[g][3][2]);
      float m5 = fmaxf(fmaxf(m0, m1), m2);
      float p  = fmaxf(fmaxf(fmaxf(m3, m4), s[g][3][3]), m5);
      p = fmaxf(p, __shfl_xor(p, 16, 64));
      p = fmaxf(p, __shfl_xor(p, 32, 64));
      pm[g] = p;
    }

    // ---- defer-rescale (THR=7 in log2; P bounded by 128)
    if (__any((pm[0] > mrun[0] + 7.0f) || (pm[1] > mrun[1] + 7.0f))) {
      #pragma unroll
      for (int g = 0; g < 2; ++g) {
        float mnew = fmaxf(mrun[g], pm[g]);
        float scl = fexp2(mrun[g] - mnew);
        mrun[g] = mnew;
        #pragma unroll
        for (int r = 0; r < 4; ++r) {
          float sq = u2f((unsigned)__builtin_amdgcn_ds_bpermute(
              (20 * h + r) * 4, (int)f2u(scl)));
          os[g][r] *= sq;
          #pragma unroll
          for (int dg = 0; dg < 4; ++dg) o[g][dg][r] *= sq;
        }
      }
    }

    // ---- P = exp2(S - mrun) -> bf16 pairs -> per-wave LDS [32q][64kv]
    #pragma unroll
    for (int g = 0; g < 2; ++g)
      #pragma unroll
      for (int c = 0; c < 4; ++c) {
        int w0 = cvtpk(fexp2(s[g][c][0] - mrun[g]),
                       fexp2(s[g][c][1] - mrun[g]));
        int w1 = cvtpk(fexp2(s[g][c][2] - mrun[g]),
                       fexp2(s[g][c][3] - mrun[g]));
        int* dst = (int*)(pb + g * 2048 + prow + ((c * 32 + h * 8) ^ pxor));
        dst[0] = w0; dst[1] = w1;
      }

    // ---- PV + row-sum (P A-frags re-read from LDS; same-wave, no barrier)
    __builtin_amdgcn_s_setprio(1);
    #pragma unroll
    for (int ch = 0; ch < 2; ++ch) {
      bf16x8 pa0 = *(const bf16x8*)(pb + prow +
                                    ((ch * 64 + h * 16) ^ pxor));
      bf16x8 pa1 = *(const bf16x8*)(pb + 2048 + prow +
                                    ((ch * 64 + h * 16) ^ pxor));
      os[0] = MFMA(pa0, ones, os[0]);
      os[1] = MFMA(pa1, ones, os[1]);
      #pragma unroll
      for (int dg = 0; dg < 4; ++dg) {
        bf16x8 vb = *(const bf16x8*)(smb + 8192 + ch * 4096 + dg * 1024);
        o[0][dg] = MFMA(pa0, vb, o[0][dg]);
        o[1][dg] = MFMA(pa1, vb, o[1][dg]);
      }
    }
    __builtin_amdgcn_s_setprio(0);
  }

  // ---- write partial O (bf16, unnormalized), m (h==0), s (x==0)
  u16* op = OP + (size_t)half * 4194304 + ((size_t)(bh * 2048 + qr0)) * 64;
  #pragma unroll
  for (int g = 0; g < 2; ++g) {
    #pragma unroll
    for (int r = 0; r < 4; ++r) {
      const int row = g * 16 + h * 4 + r;
      #pragma unroll
      for (int dg = 0; dg < 4; ++dg)
        op[(size_t)row * 64 + dg * 16 + x] = f2bf(o[g][dg][r]);
      if (x == 0)
        Sm[half * 65536 + bh * 2048 + qr0 + g * 16 + h * 4 + r] = os[g][r];
    }
    if (h == 0)
      Mm[half * 65536 + bh * 2048 + qr0 + g * 16 + x] = mrun[g];
  }
}

// ---------------- combine: merge the two KV halves --------------------------
__global__ __launch_bounds__(256) void k_combine(
    const u16* __restrict__ OP, const float* __restrict__ Mm,
    const float* __restrict__ Sm, u16* __restrict__ AO) {
  const int gi = blockIdx.x * 256 + threadIdx.x;
  const int d4 = (gi & 15) * 4;
  const int rb = gi >> 4;                    // bh*2048 + row
  const float m1 = Mm[rb], m2 = Mm[65536 + rb];
  const float s1 = Sm[rb], s2 = Sm[65536 + rb];
  const float m = fmaxf(m1, m2);
  const float a1 = fexp2(m1 - m), a2 = fexp2(m2 - m);
  const float inv = 1.0f / (s1 * a1 + s2 * a2);
  const float w1 = a1 * inv, w2 = a2 * inv;
  s16x4 p1 = *(const s16x4*)&OP[(size_t)rb * 64 + d4];
  s16x4 p2 = *(const s16x4*)&OP[4194304 + (size_t)rb * 64 + d4];
  const int bh = rb >> 11, row = rb & 2047;
  const int b = bh >> 3, head = bh & 7;
  s16x4 r_;
  #pragma unroll
  for (int j = 0; j < 4; ++j)
    r_[j] = (short)f2bf(bf2f((u16)p1[j]) * w1 + bf2f((u16)p2[j]) * w2);
  *(s16x4*)&AO[((size_t)(b * 2048 + row)) * 512 + head * 64 + d4] = r_;
}

// ---------------------------------------------------------------------------
extern "C" void kernel_launch(void* const* d_in, const int* in_sizes, int n_in,
                              void* d_out, int out_size, void* d_ws, size_t ws_size,
                              hipStream_t stream) {
  const float* x    = (const float*)d_in[0];
  const float* wqkv = (const float*)d_in[1];
  const float* wout = (const float*)d_in[2];
  const float* bout = (const float*)d_in[3];
  float* out = (float*)d_out;

  char* w = (char*)d_ws;
  u16* xh  = (u16*)(w + 0);           // 8192x512 bf16 (dead after qkv)
  u16* wqh = (u16*)(w + 16777216);    // WqkvT [1536][512] (dead after qkv)
  u16* woh = (u16*)(w + 19922944);    // WoutT [512][512] (live to end)
  u16* Qb  = (u16*)(w + 20971520);    // [32][2048][64] bf16 (pre-scaled)
  u16* Kb  = (u16*)(w + 37748736);    // [32][2048][64] bf16
  u16* Vt  = (u16*)(w + 46137344);    // [32][64][2048] bf16
  u16* AO  = (u16*)(w + 54525952);    // [8192][512] bf16; end 62914560
  // Split-KV partials (alias dead phase-1 regions):
  u16*   OP = (u16*)(w + 0);          // [2][4194304] bf16 = 16MB
  float* Mm = (float*)(w + 16777216); // [2][65536] f32
  float* Sm = (float*)(w + 17301504); // [2][65536] f32

  k_cast <<<4096, 256, 0, stream>>>(x, xh, 4194304);
  k_tcast<<<3072, 256, 0, stream>>>(wqkv, wqh, 1536, 786432);
  k_tcast<<<1024, 256, 0, stream>>>(wout, woh, 512, 262144);
  k_gemm_qkv<<<dim3(64, 12), 256, 0, stream>>>(xh, wqh, Qb, Kb, Vt);
  k_attn<<<512, 512, 0, stream>>>(Qb, Kb, Vt, OP, Mm, Sm);
  k_combine<<<4096, 256, 0, stream>>>(OP, Mm, Sm, AO);
  k_gemm_out<<<dim3(64, 4), 256, 0, stream>>>(AO, woh, bout, out);
}

// Round 15
// 96.458 us; speedup vs baseline: 1.1871x; 1.1062x over previous
//
#include <hip/hip_runtime.h>
#include <hip/hip_bf16.h>
#include <math.h>
#include <stdint.h>

// ---------------------------------------------------------------------------
// Attention (B=4, N=2048, D=512, H=8, Dh=64) for MI355X.
// Precision plan (threshold 6.48e-3; measured floor 1.95e-3):
//   x@Wqkv: 1-term bf16.  QK^T: bf16.  PV: bf16 P,V.  AO bf16; out GEMM
//   1-term.  Split-KV partials bf16, m/s f32.
// R15: GEMM core rebuilt with attn-proven staging: double-buffered A/B LDS
// (2x16KB ping-pong), raw s_barrier + counted vmcnt(4), no vmcnt(0) drain in
// the K-loop (removes the m97 barrier-drain stall that made 1-term QKV no
// faster than 2-term). Attention kernel = R14 (51us, unchanged).
// ---------------------------------------------------------------------------

typedef unsigned short u16;
typedef __attribute__((ext_vector_type(4))) float f32x4;
typedef __attribute__((ext_vector_type(8))) short bf16x8;   // 8 bf16 = 4 VGPRs
typedef __attribute__((ext_vector_type(4))) short s16x4;

#define AS1 __attribute__((address_space(1)))
#define AS3 __attribute__((address_space(3)))
#define MFMA(a, b, c) __builtin_amdgcn_mfma_f32_16x16x32_bf16(a, b, c, 0, 0, 0)
#define QSCALE 0.180336880f   /* 0.125 * log2(e): logits in log2 domain */

__device__ __forceinline__ u16 f2bf(float f) {
  union { float f; unsigned u; } v; v.f = f;
  unsigned r = v.u + 0x7FFFu + ((v.u >> 16) & 1u);   // RNE
  return (u16)(r >> 16);
}
__device__ __forceinline__ float bf2f(u16 b) {
  union { unsigned u; float f; } v; v.u = ((unsigned)b) << 16; return v.f;
}
__device__ __forceinline__ void gld16(const u16* g, u16* l) {
  __builtin_amdgcn_global_load_lds((const AS1 void*)g, (AS3 void*)l, 16, 0, 0);
}
__device__ __forceinline__ float u2f(unsigned u) {
  union { unsigned u; float f; } v; v.u = u; return v.f;
}
__device__ __forceinline__ unsigned f2u(float f) {
  union { float f; unsigned u; } v; v.f = f; return v.u;
}
__device__ __forceinline__ int cvtpk(float lo, float hi) {
  int r; asm("v_cvt_pk_bf16_f32 %0, %1, %2" : "=v"(r) : "v"(lo), "v"(hi));
  return r;
}
__device__ __forceinline__ float fexp2(float x) {
  float r; asm("v_exp_f32 %0, %1" : "=v"(r) : "v"(x));
  return r;
}

// ---------------- prep kernels -------------------------------------------
__global__ void k_cast(const float* __restrict__ s, u16* __restrict__ h, int n) {
  int i = (blockIdx.x * 256 + threadIdx.x) * 4;
  if (i < n) {
    f32x4 v = *(const f32x4*)&s[i];
    s16x4 hh;
    #pragma unroll
    for (int j = 0; j < 4; ++j) hh[j] = (short)f2bf(v[j]);
    *(s16x4*)&h[i] = hh;
  }
}

// src [512][N] row-major -> dst [N][512] transposed bf16 cast
__global__ void k_tcast(const float* __restrict__ s, u16* __restrict__ h,
                        int N, int total) {
  int i = blockIdx.x * 256 + threadIdx.x;          // i = n*512 + k
  if (i < total) {
    int n = i >> 9, k = i & 511;
    h[i] = f2bf(s[(size_t)k * N + n]);
  }
}

// ---------------- GEMM core: C[128x128], K=512, BK=32, 1-term, dbuf --------
// LDS 32KB: buf0 {A 8K @0, B 8K @8K}, buf1 @16K. Raw s_barrier + vmcnt(4)
// counted prefetch (attn-proven T3/T4 pattern; no full drain in loop).
__device__ __forceinline__ void gemm_core(
    const u16* __restrict__ Ah, const u16* __restrict__ Bh,
    char* sm, int rowA, int rowB, int tid, f32x4 (&acc)[4][4]) {
  const int wid = tid >> 6, lane = tid & 63;
  const int x = lane & 15, h = lane >> 4;
  const int wr = wid >> 1, wc = wid & 1;
  const int d0 = tid * 16;
  const int lg0 = d0 ^ (((d0 >> 7) & 7) << 4);
  const int srow = lg0 >> 6;              // 0..63 (+r*64)
  const int scol = (lg0 & 63) >> 1;       // u16 col within 32-wide row
  const int swk = ((lane >> 1) & 7) << 4;
  const int rdoA = ((wr * 64 + x) * 64 + h * 16) ^ swk;
  const int rdoB = (((wc * 64 + x) * 64 + h * 16) ^ swk) + 8192;

  {  // stage kt=0 -> buf0 (4 loads/thread)
    #pragma unroll
    for (int r = 0; r < 2; ++r) {
      const size_t ga = (size_t)(rowA + r * 64 + srow) * 512 + scol;
      const size_t gb = (size_t)(rowB + r * 64 + srow) * 512 + scol;
      gld16(Ah + ga, (u16*)(sm + r * 4096 + d0));
      gld16(Bh + gb, (u16*)(sm + 8192 + r * 4096 + d0));
    }
  }

  for (int kt = 0; kt < 16; ++kt) {
    const int bb = (kt & 1) * 16384;
    __builtin_amdgcn_s_barrier();               // alt buf free
    if (kt < 15) {
      const int kofs = (kt + 1) * 32;
      char* buf = sm + (16384 - bb);
      #pragma unroll
      for (int r = 0; r < 2; ++r) {
        const size_t ga = (size_t)(rowA + r * 64 + srow) * 512 + kofs + scol;
        const size_t gb = (size_t)(rowB + r * 64 + srow) * 512 + kofs + scol;
        gld16(Ah + ga, (u16*)(buf + r * 4096 + d0));
        gld16(Bh + gb, (u16*)(buf + 8192 + r * 4096 + d0));
      }
      asm volatile("s_waitcnt vmcnt(4)" ::: "memory");  // tile kt landed
    } else {
      asm volatile("s_waitcnt vmcnt(0)" ::: "memory");
    }
    __builtin_amdgcn_s_barrier();               // tile kt ready for everyone

    bf16x8 a_h[4], b_h[4];
    #pragma unroll
    for (int i = 0; i < 4; ++i)
      a_h[i] = *(const bf16x8*)(sm + bb + rdoA + i * 1024);
    #pragma unroll
    for (int j = 0; j < 4; ++j)
      b_h[j] = *(const bf16x8*)(sm + bb + rdoB + j * 1024);
    __builtin_amdgcn_s_setprio(1);
    #pragma unroll
    for (int i = 0; i < 4; ++i)
      #pragma unroll
      for (int j = 0; j < 4; ++j)
        acc[i][j] = MFMA(a_h[i], b_h[j], acc[i][j]);
    __builtin_amdgcn_s_setprio(0);
  }
}

// ---------------- QKV projection (1-term) ----------------------------------
__global__ __launch_bounds__(256) void k_gemm_qkv(
    const u16* __restrict__ Ah, const u16* __restrict__ Bh,
    u16* __restrict__ Qb, u16* __restrict__ Kb, u16* __restrict__ Vt) {
  __shared__ __align__(1024) char sm[32768];
  const int tid = threadIdx.x, lane = tid & 63, wid = tid >> 6;
  const int x = lane & 15, h = lane >> 4;
  const int wr = wid >> 1, wc = wid & 1;
  const int rowA = blockIdx.x * 128, rowB = blockIdx.y * 128;
  f32x4 acc[4][4] = {};
  gemm_core(Ah, Bh, sm, rowA, rowB, tid, acc);

  #pragma unroll
  for (int i = 0; i < 4; ++i)
    #pragma unroll
    for (int j = 0; j < 4; ++j) {
      const int n = rowB + wc * 64 + j * 16 + x;
      const int which = n >> 9;
      const int hh = (n >> 6) & 7, d = n & 63;
      const int m0 = rowA + wr * 64 + i * 16 + h * 4;
      const int b = m0 >> 11, is0 = m0 & 2047;
      if (which == 0) {
        #pragma unroll
        for (int r = 0; r < 4; ++r) {
          const size_t idx = ((size_t)((b * 8 + hh) * 2048 + is0 + r)) * 64 + d;
          Qb[idx] = f2bf(acc[i][j][r] * QSCALE);
        }
      } else if (which == 1) {
        #pragma unroll
        for (int r = 0; r < 4; ++r) {
          const size_t idx = ((size_t)((b * 8 + hh) * 2048 + is0 + r)) * 64 + d;
          Kb[idx] = f2bf(acc[i][j][r]);
        }
      } else {
        s16x4 vv;
        #pragma unroll
        for (int r = 0; r < 4; ++r) vv[r] = (short)f2bf(acc[i][j][r]);
        *(s16x4*)&Vt[((size_t)((b * 8 + hh) * 64 + d)) * 2048 + is0] = vv;
      }
    }
}

// ---------------- output projection (1-term bf16) --------------------------
__global__ __launch_bounds__(256) void k_gemm_out(
    const u16* __restrict__ Ah, const u16* __restrict__ Bh,
    const float* __restrict__ bias, float* __restrict__ out) {
  __shared__ __align__(1024) char sm[32768];
  const int tid = threadIdx.x, lane = tid & 63, wid = tid >> 6;
  const int x = lane & 15, h = lane >> 4;
  const int wr = wid >> 1, wc = wid & 1;
  const int rowA = blockIdx.x * 128, rowB = blockIdx.y * 128;
  f32x4 acc[4][4] = {};
  gemm_core(Ah, Bh, sm, rowA, rowB, tid, acc);

  #pragma unroll
  for (int i = 0; i < 4; ++i)
    #pragma unroll
    for (int j = 0; j < 4; ++j) {
      const int n = rowB + wc * 64 + j * 16 + x;
      #pragma unroll
      for (int r = 0; r < 4; ++r) {
        const int m = rowA + wr * 64 + i * 16 + h * 4 + r;
        out[(size_t)m * 512 + n] = acc[i][j][r] + bias[n];
      }
    }
}

// ---------------- flash attention, split-KV half, 8-wave blocks -------------
// (unchanged from R14: 51us, occupancy 33%)
__global__ __launch_bounds__(512, 2) void k_attn(
    const u16* __restrict__ Qb,
    const u16* __restrict__ Kb, const u16* __restrict__ Vt,
    u16* __restrict__ OP,          // [2][32*2048*64] bf16 (+half*4194304)
    float* __restrict__ Mm,        // [2][65536]
    float* __restrict__ Sm) {      // [2][65536]
  __shared__ __align__(1024) char sm[65536];
  const int tid = threadIdx.x, wid = tid >> 6, lane = tid & 63;
  const int x = lane & 15, h = lane >> 4;

  // XCD swizzle: 4 bh per XCD; halves of same (qb,bh) on same XCD
  const int fid = blockIdx.x;
  const int l = (fid & 7) * 64 + (fid >> 3);
  const int half = l & 1, qb = (l >> 1) & 7, bh = l >> 4;

  const size_t base = (size_t)bh * 2048 * 64;   // Q/K [bh][2048][64]; Vt [bh][64][2048]
  const int qr0 = qb * 256 + wid * 32;
  const size_t kv0 = (size_t)half * 1024;        // first kv of this half

  // Q B-frags per group g: lane (x,h) holds Q[qr0+g*16+x][d=ks*32+h*8+j]
  bf16x8 qh[2][2];
  #pragma unroll
  for (int g = 0; g < 2; ++g) {
    const size_t rq = base + (size_t)(qr0 + g * 16 + x) * 64 + h * 8;
    #pragma unroll
    for (int ks = 0; ks < 2; ++ks)
      qh[g][ks] = *(const bf16x8*)&Qb[rq + ks * 32];
  }

  bf16x8 ones;
  #pragma unroll
  for (int j = 0; j < 8; ++j) ones[j] = (short)0x3F80;   // bf16 1.0

  // staging map (512 thr): K image [0,8K) dest db=tid*16; V image [8K,16K)
  const int db = tid * 16;
  const int lg = db ^ (((db >> 7) & 7) << 4);
  const int sks  = db >> 12;            // chunk (bit 12 untouched by xor)
  const int srow = (lg >> 6) & 63;
  const int scb  = (lg & 63) >> 1;
  const size_t offK = (size_t)srow * 64 + sks * 32 + scb;    // + kvb*64
  const size_t offV = (size_t)srow * 2048 + sks * 32 + scb;  // + kvb

  const int swk = ((lane >> 1) & 7) << 4;   // read xor for 64B-row tiles
  const int rdo = (x * 64 + h * 16) ^ swk;  // per-lane K/V read base offset
  char* const pb = sm + 32768 + wid * 4096; // per-wave P buffer [32q][64kv]
  const int pxor = (x & 7) << 4;            // P row swizzle
  const int prow = x * 128;                 // P row base (g adds 2048)

  float mrun[2] = {-INFINITY, -INFINITY};
  f32x4 o[2][4] = {};
  f32x4 os[2] = {};

  {  // stage tile 0 of this half -> buf0 (2 loads/thread)
    gld16(Kb + base + kv0 * 64 + offK, (u16*)(sm + db));
    gld16(Vt + base + kv0 + offV,      (u16*)(sm + 8192 + db));
  }

  for (int kv = 0; kv < 16; ++kv) {
    const int bb = (kv & 1) * 16384;
    __builtin_amdgcn_s_barrier();
    if (kv < 15) {
      const size_t kvb = kv0 + (size_t)(kv + 1) * 64;
      char* buf = sm + (16384 - bb);
      gld16(Kb + base + kvb * 64 + offK, (u16*)(buf + db));
      gld16(Vt + base + kvb + offV,      (u16*)(buf + 8192 + db));
      asm volatile("s_waitcnt vmcnt(2)" ::: "memory");  // prev tile landed
    } else {
      asm volatile("s_waitcnt vmcnt(0)" ::: "memory");
    }
    __builtin_amdgcn_s_barrier();

    const char* smb = sm + bb + rdo;

    // ---- S^T = K Q^T (bf16; Q pre-scaled by 0.125*log2e)
    f32x4 s[2][4] = {};
    __builtin_amdgcn_s_setprio(1);
    #pragma unroll
    for (int c = 0; c < 4; ++c)
      #pragma unroll
      for (int ks = 0; ks < 2; ++ks) {
        bf16x8 kb_ = *(const bf16x8*)(smb + ks * 4096 + c * 1024);
        s[0][c] = MFMA(kb_, qh[0][ks], s[0][c]);
        s[1][c] = MFMA(kb_, qh[1][ks], s[1][c]);
      }
    __builtin_amdgcn_s_setprio(0);

    // ---- per-group row max (16 local) + 2-shfl cross reduce over h-lanes
    float pm[2];
    #pragma unroll
    for (int g = 0; g < 2; ++g) {
      float m0 = fmaxf(fmaxf(s[g][0][0], s[g][0][1]), s[g][0][2]);
      float m1 = fmaxf(fmaxf(s[g][0][3], s[g][1][0]), s[g][1][1]);
      float m2 = fmaxf(fmaxf(s[g][1][2], s[g][1][3]), s[g][2][0]);
      float m3 = fmaxf(fmaxf(s[g][2][1], s[g][2][2]), s[g][2][3]);
      float m4 = fmaxf(fmaxf(s[g][3][0], s[g][3][1]), s[g][3][2]);
      float m5 = fmaxf(fmaxf(m0, m1), m2);
      float p  = fmaxf(fmaxf(fmaxf(m3, m4), s[g][3][3]), m5);
      p = fmaxf(p, __shfl_xor(p, 16, 64));
      p = fmaxf(p, __shfl_xor(p, 32, 64));
      pm[g] = p;
    }

    // ---- defer-rescale (THR=7 in log2; P bounded by 128)
    if (__any((pm[0] > mrun[0] + 7.0f) || (pm[1] > mrun[1] + 7.0f))) {
      #pragma unroll
      for (int g = 0; g < 2; ++g) {
        float mnew = fmaxf(mrun[g], pm[g]);
        float scl = fexp2(mrun[g] - mnew);
        mrun[g] = mnew;
        #pragma unroll
        for (int r = 0; r < 4; ++r) {
          float sq = u2f((unsigned)__builtin_amdgcn_ds_bpermute(
              (20 * h + r) * 4, (int)f2u(scl)));
          os[g][r] *= sq;
          #pragma unroll
          for (int dg = 0; dg < 4; ++dg) o[g][dg][r] *= sq;
        }
      }
    }

    // ---- P = exp2(S - mrun) -> bf16 pairs -> per-wave LDS [32q][64kv]
    #pragma unroll
    for (int g = 0; g < 2; ++g)
      #pragma unroll
      for (int c = 0; c < 4; ++c) {
        int w0 = cvtpk(fexp2(s[g][c][0] - mrun[g]),
                       fexp2(s[g][c][1] - mrun[g]));
        int w1 = cvtpk(fexp2(s[g][c][2] - mrun[g]),
                       fexp2(s[g][c][3] - mrun[g]));
        int* dst = (int*)(pb + g * 2048 + prow + ((c * 32 + h * 8) ^ pxor));
        dst[0] = w0; dst[1] = w1;
      }

    // ---- PV + row-sum (P A-frags re-read from LDS; same-wave, no barrier)
    __builtin_amdgcn_s_setprio(1);
    #pragma unroll
    for (int ch = 0; ch < 2; ++ch) {
      bf16x8 pa0 = *(const bf16x8*)(pb + prow +
                                    ((ch * 64 + h * 16) ^ pxor));
      bf16x8 pa1 = *(const bf16x8*)(pb + 2048 + prow +
                                    ((ch * 64 + h * 16) ^ pxor));
      os[0] = MFMA(pa0, ones, os[0]);
      os[1] = MFMA(pa1, ones, os[1]);
      #pragma unroll
      for (int dg = 0; dg < 4; ++dg) {
        bf16x8 vb = *(const bf16x8*)(smb + 8192 + ch * 4096 + dg * 1024);
        o[0][dg] = MFMA(pa0, vb, o[0][dg]);
        o[1][dg] = MFMA(pa1, vb, o[1][dg]);
      }
    }
    __builtin_amdgcn_s_setprio(0);
  }

  // ---- write partial O (bf16, unnormalized), m (h==0), s (x==0)
  u16* op = OP + (size_t)half * 4194304 + ((size_t)(bh * 2048 + qr0)) * 64;
  #pragma unroll
  for (int g = 0; g < 2; ++g) {
    #pragma unroll
    for (int r = 0; r < 4; ++r) {
      const int row = g * 16 + h * 4 + r;
      #pragma unroll
      for (int dg = 0; dg < 4; ++dg)
        op[(size_t)row * 64 + dg * 16 + x] = f2bf(o[g][dg][r]);
      if (x == 0)
        Sm[half * 65536 + bh * 2048 + qr0 + g * 16 + h * 4 + r] = os[g][r];
    }
    if (h == 0)
      Mm[half * 65536 + bh * 2048 + qr0 + g * 16 + x] = mrun[g];
  }
}

// ---------------- combine: merge the two KV halves --------------------------
__global__ __launch_bounds__(256) void k_combine(
    const u16* __restrict__ OP, const float* __restrict__ Mm,
    const float* __restrict__ Sm, u16* __restrict__ AO) {
  const int gi = blockIdx.x * 256 + threadIdx.x;
  const int d4 = (gi & 15) * 4;
  const int rb = gi >> 4;                    // bh*2048 + row
  const float m1 = Mm[rb], m2 = Mm[65536 + rb];
  const float s1 = Sm[rb], s2 = Sm[65536 + rb];
  const float m = fmaxf(m1, m2);
  const float a1 = fexp2(m1 - m), a2 = fexp2(m2 - m);
  const float inv = 1.0f / (s1 * a1 + s2 * a2);
  const float w1 = a1 * inv, w2 = a2 * inv;
  s16x4 p1 = *(const s16x4*)&OP[(size_t)rb * 64 + d4];
  s16x4 p2 = *(const s16x4*)&OP[4194304 + (size_t)rb * 64 + d4];
  const int bh = rb >> 11, row = rb & 2047;
  const int b = bh >> 3, head = bh & 7;
  s16x4 r_;
  #pragma unroll
  for (int j = 0; j < 4; ++j)
    r_[j] = (short)f2bf(bf2f((u16)p1[j]) * w1 + bf2f((u16)p2[j]) * w2);
  *(s16x4*)&AO[((size_t)(b * 2048 + row)) * 512 + head * 64 + d4] = r_;
}

// ---------------------------------------------------------------------------
extern "C" void kernel_launch(void* const* d_in, const int* in_sizes, int n_in,
                              void* d_out, int out_size, void* d_ws, size_t ws_size,
                              hipStream_t stream) {
  const float* x    = (const float*)d_in[0];
  const float* wqkv = (const float*)d_in[1];
  const float* wout = (const float*)d_in[2];
  const float* bout = (const float*)d_in[3];
  float* out = (float*)d_out;

  char* w = (char*)d_ws;
  u16* xh  = (u16*)(w + 0);           // 8192x512 bf16 (dead after qkv)
  u16* wqh = (u16*)(w + 16777216);    // WqkvT [1536][512] (dead after qkv)
  u16* woh = (u16*)(w + 19922944);    // WoutT [512][512] (live to end)
  u16* Qb  = (u16*)(w + 20971520);    // [32][2048][64] bf16 (pre-scaled)
  u16* Kb  = (u16*)(w + 37748736);    // [32][2048][64] bf16
  u16* Vt  = (u16*)(w + 46137344);    // [32][64][2048] bf16
  u16* AO  = (u16*)(w + 54525952);    // [8192][512] bf16; end 62914560
  // Split-KV partials (alias dead phase-1 regions):
  u16*   OP = (u16*)(w + 0);          // [2][4194304] bf16 = 16MB
  float* Mm = (float*)(w + 16777216); // [2][65536] f32
  float* Sm = (float*)(w + 17301504); // [2][65536] f32

  k_cast <<<4096, 256, 0, stream>>>(x, xh, 4194304);
  k_tcast<<<3072, 256, 0, stream>>>(wqkv, wqh, 1536, 786432);
  k_tcast<<<1024, 256, 0, stream>>>(wout, woh, 512, 262144);
  k_gemm_qkv<<<dim3(64, 12), 256, 0, stream>>>(xh, wqh, Qb, Kb, Vt);
  k_attn<<<512, 512, 0, stream>>>(Qb, Kb, Vt, OP, Mm, Sm);
  k_combine<<<4096, 256, 0, stream>>>(OP, Mm, Sm, AO);
  k_gemm_out<<<dim3(64, 4), 256, 0, stream>>>(AO, woh, bout, out);
}